// Round 7
// baseline (569.173 us; speedup 1.0000x reference)
//
#include <hip/hip_runtime.h>

typedef unsigned short u16;
typedef unsigned int u32;
typedef __attribute__((ext_vector_type(8))) short short8;
typedef __attribute__((ext_vector_type(4))) float f32x4;
typedef __attribute__((ext_vector_type(4))) u32 u32x4;
typedef __attribute__((ext_vector_type(2))) u32 u32x2;

#define NPT 128
#define DIM 512
#define KT 48
#define KC 32
#define BPB 16   // batches per block (persistent pipeline)

__device__ __forceinline__ u16 f2bf(float f) {
    unsigned u = __builtin_bit_cast(unsigned, f);
    return (u16)((u + 0x7FFFu + ((u >> 16) & 1u)) >> 16);
}

__device__ __forceinline__ u32 cvtpk(float lo, float hi) {
    u32 r;
    asm("v_cvt_pk_bf16_f32 %0, %1, %2" : "=v"(r) : "v"(lo), "v"(hi));
    return r;
}

// LDS-only barrier: producer-side lgkmcnt drain + raw s_barrier.
// Deliberately does NOT drain vmcnt, so register-destined global prefetch
// loads stay in flight across it (unlike __syncthreads()).
__device__ __forceinline__ void lds_barrier() {
    asm volatile("s_waitcnt lgkmcnt(0)" ::: "memory");
    __builtin_amdgcn_s_barrier();
}

// bank swizzle: 16B-granular XOR inside a 1KB row; distinct for rows n..n+7
// (phase-1 groups) AND for rows n, n+8, n+16, n+24 (phase-2 gather groups)
__device__ __forceinline__ int swz(int n) {
    return ((n & 7) ^ ((n >> 3) & 7)) << 4;
}

// Fold BN into clusters: cTs[k][d] = bf16(clusters[d][k] * s_k), t[k] = b_k - rm_k*s_k
__global__ void prep_kernel(const float* __restrict__ clusters,
                            const float* __restrict__ bn_w,
                            const float* __restrict__ bn_b,
                            const float* __restrict__ bn_rm,
                            const float* __restrict__ bn_rv,
                            u16* __restrict__ cTs,
                            float* __restrict__ tvec) {
    const int k = blockIdx.x;
    const float s = bn_w[k] * rsqrtf(bn_rv[k] + 1e-5f);
    if (threadIdx.x == 0) tvec[k] = bn_b[k] - bn_rm[k] * s;
    for (int d = threadIdx.x; d < DIM; d += blockDim.x)
        cTs[k * DIM + d] = f2bf(clusters[d * KT + k] * s);
}

// prefetch: issue 8 loads (4 rows) into t[tb..tb+7]; convert group to stg
#define PREF_ISSUE(g, tb)                                                    \
    do {                                                                     \
        _Pragma("unroll")                                                    \
        for (int rr = 0; rr < 4; ++rr) {                                     \
            int i = (g) * 4 + rr;                                            \
            t[(tb) + 2 * rr]     = *(const f32x4*)(nx + i * DIM + lane * 8); \
            t[(tb) + 2 * rr + 1] = *(const f32x4*)(nx + i * DIM + lane * 8 + 4); \
        }                                                                    \
    } while (0)

#define PREF_CONV(g, tb)                                                     \
    do {                                                                     \
        _Pragma("unroll")                                                    \
        for (int rr = 0; rr < 4; ++rr) {                                     \
            int i = (g) * 4 + rr;                                            \
            u32x4 w;                                                         \
            w[0] = cvtpk(t[(tb) + 2 * rr][0],     t[(tb) + 2 * rr][1]);      \
            w[1] = cvtpk(t[(tb) + 2 * rr][2],     t[(tb) + 2 * rr][3]);      \
            w[2] = cvtpk(t[(tb) + 2 * rr + 1][0], t[(tb) + 2 * rr + 1][1]);  \
            w[3] = cvtpk(t[(tb) + 2 * rr + 1][2], t[(tb) + 2 * rr + 1][3]);  \
            stg[i] = w;                                                      \
        }                                                                    \
    } while (0)

__global__ __launch_bounds__(512)
void vlad_kernel(const float* __restrict__ x,
                 const float* __restrict__ c2,     // [512][32] fp32
                 const u16* __restrict__ cTs,      // [48][512] bf16
                 const float* __restrict__ tvec,   // [48]
                 float* __restrict__ out) {
    __shared__ __align__(16) u16 xs[NPT * DIM];    // 128 KB, swizzled row-major
    __shared__ __align__(16) u16 aT[KC][136];      // assignment^T
    __shared__ float asum_part[8][KC];
    __shared__ float colsq_part[8][KC];

    const int tid  = threadIdx.x;
    const int wave = tid >> 6;
    const int lane = tid & 63;
    const int lr   = lane & 15;
    const int lg   = lane >> 4;

    const int b0i = blockIdx.x * BPB;

    const float t0 = tvec[lr], t1 = tvec[16 + lr], t2 = tvec[32 + lr];

    // ---- prologue: stage batch b0i (wave-self: wave w rows [16w,16w+16)) ----
    {
        const float* gxw = x + (size_t)b0i * (NPT * DIM) + (wave * 16) * DIM;
        #pragma unroll
        for (int bt = 0; bt < 4; ++bt) {
            f32x4 tmp[8];
            #pragma unroll
            for (int i = 0; i < 8; ++i) {
                int it = bt * 8 + i;
                tmp[i] = *(const f32x4*)(gxw + (it >> 1) * DIM + (it & 1) * 256 + lane * 4);
            }
            #pragma unroll
            for (int i = 0; i < 8; ++i) {
                int it = bt * 8 + i;
                int r = wave * 16 + (it >> 1);
                u32x2 w2;
                w2[0] = cvtpk(tmp[i][0], tmp[i][1]);
                w2[1] = cvtpk(tmp[i][2], tmp[i][3]);
                int off = ((it & 1) * 512 + lane * 8) ^ swz(r);
                *(u32x2*)((char*)xs + r * 1024 + off) = w2;
            }
        }
    }

    for (int m = 0; m < BPB; ++m) {
        const int bm = b0i + m;
        const bool prefOK = (m + 1 < BPB);
        const float* nx = x + (size_t)(bm + 1) * (NPT * DIM) + (wave * 16) * DIM;
        f32x4 t[16];
        u32x4 stg[16];

        // ---- phase 1: logits for own 16 rows (xs holds batch bm) ----
        f32x4 acc0 = {0.f,0.f,0.f,0.f}, acc1 = {0.f,0.f,0.f,0.f}, acc2 = {0.f,0.f,0.f,0.f};
        {
            const int nrow = wave * 16 + lr;
            const int rowbase = nrow * 1024;
            const int sw = swz(nrow);
            #pragma unroll 2
            for (int step = 0; step < 16; ++step) {
                const int d0 = step * 32 + lg * 8;
                short8 af = *(const short8*)((const char*)xs + (rowbase + ((2 * d0) ^ sw)));
                short8 bb0 = *(const short8*)(cTs + (0 * 16 + lr) * DIM + d0);
                short8 bb1 = *(const short8*)(cTs + (1 * 16 + lr) * DIM + d0);
                short8 bb2 = *(const short8*)(cTs + (2 * 16 + lr) * DIM + d0);
                acc0 = __builtin_amdgcn_mfma_f32_16x16x32_bf16(af, bb0, acc0, 0, 0, 0);
                acc1 = __builtin_amdgcn_mfma_f32_16x16x32_bf16(af, bb1, acc1, 0, 0, 0);
                acc2 = __builtin_amdgcn_mfma_f32_16x16x32_bf16(af, bb2, acc2, 0, 0, 0);
            }
        }

        // ---- prefetch issue g0,g1 (after ALL cTs loads; softmax/phase2 are
        //      vmcnt-free, so these stream under them) ----
        if (prefOK) { PREF_ISSUE(0, 0); PREF_ISSUE(1, 8); }

        // ---- softmax over 48, keep 32; aT bf16; per-wave asum partials ----
        {
            float a0[4], a1[4];
            #pragma unroll
            for (int r = 0; r < 4; ++r) {
                float l0 = acc0[r] + t0, l1 = acc1[r] + t1, l2 = acc2[r] + t2;
                float mx = fmaxf(fmaxf(l0, l1), l2);
                #pragma unroll
                for (int o = 1; o < 16; o <<= 1) mx = fmaxf(mx, __shfl_xor(mx, o));
                float e0 = __expf(l0 - mx), e1 = __expf(l1 - mx), e2 = __expf(l2 - mx);
                float s = e0 + e1 + e2;
                #pragma unroll
                for (int o = 1; o < 16; o <<= 1) s += __shfl_xor(s, o);
                float inv = 1.0f / s;
                a0[r] = e0 * inv; a1[r] = e1 * inv;
            }
            float p0 = 0.f, p1 = 0.f;
            #pragma unroll
            for (int r = 0; r < 4; ++r) {
                int n = wave * 16 + lg * 4 + r;
                aT[lr][n]      = f2bf(a0[r]);
                aT[16 + lr][n] = f2bf(a1[r]);
                p0 += a0[r]; p1 += a1[r];
            }
            p0 += __shfl_xor(p0, 16); p0 += __shfl_xor(p0, 32);
            p1 += __shfl_xor(p1, 16); p1 += __shfl_xor(p1, 32);
            if (lane < 16) { asum_part[wave][lane] = p0; asum_part[wave][16 + lane] = p1; }
        }
        lds_barrier();   // b1: aT + asum_part ready (vmcnt NOT drained)

        // ---- phase 2 (LDS-only consumer => safe window for prefetch) ----
        f32x4 vacc[4][2];
        #pragma unroll
        for (int i = 0; i < 4; ++i) {
            vacc[i][0] = (f32x4){0.f,0.f,0.f,0.f};
            vacc[i][1] = (f32x4){0.f,0.f,0.f,0.f};
        }
        #pragma unroll
        for (int ns = 0; ns < 4; ++ns) {
            if (prefOK) {
                if (ns == 0) { PREF_CONV(0, 0); PREF_ISSUE(2, 0); }
                if (ns == 1) { PREF_CONV(1, 8); PREF_ISSUE(3, 8); }
                if (ns == 2) { PREF_CONV(2, 0); }
                if (ns == 3) { PREF_CONV(3, 8); }
            }
            short8 bf0 = *(const short8*)(&aT[lr][ns * 32 + lg * 8]);
            short8 bf1 = *(const short8*)(&aT[16 + lr][ns * 32 + lg * 8]);
            const int n0 = ns * 32 + lg * 8;
            const int q  = (ns * 4 + lg) & 7;
            const char* pbase = (const char*)xs + n0 * 1024;
            #pragma unroll
            for (int dti = 0; dti < 4; ++dti) {
                const int d = (wave * 4 + dti) * 16 + lr;
                const int twod = 2 * d;
                short8 af;
                #pragma unroll
                for (int j = 0; j < 8; ++j)
                    af[j] = *(const short*)(pbase + j * 1024 + (twod ^ ((j ^ q) << 4)));
                vacc[dti][0] = __builtin_amdgcn_mfma_f32_16x16x32_bf16(af, bf0, vacc[dti][0], 0, 0, 0);
                vacc[dti][1] = __builtin_amdgcn_mfma_f32_16x16x32_bf16(af, bf1, vacc[dti][1], 0, 0, 0);
            }
        }
        lds_barrier();   // e: all phase-2 xs/aT reads complete

        // ---- write prefetched batch into xs (own rows; wave-self ordering) ----
        if (prefOK) {
            #pragma unroll
            for (int i = 0; i < 16; ++i) {
                int r = wave * 16 + i;
                *(u32x4*)((char*)xs + r * 1024 + ((lane * 16) ^ swz(r))) = stg[i];
            }
        }

        // ---- epilogue ----
        float as0 = 0.f, as1 = 0.f;
        #pragma unroll
        for (int w2 = 0; w2 < 8; ++w2) {
            as0 += asum_part[w2][lr];
            as1 += asum_part[w2][16 + lr];
        }
        float cs0 = 0.f, cs1 = 0.f;
        #pragma unroll
        for (int dti = 0; dti < 4; ++dti) {
            #pragma unroll
            for (int r = 0; r < 4; ++r) {
                int d = (wave * 4 + dti) * 16 + lg * 4 + r;
                float v0 = vacc[dti][0][r] - as0 * c2[d * KC + lr];
                float v1 = vacc[dti][1][r] - as1 * c2[d * KC + 16 + lr];
                vacc[dti][0][r] = v0; vacc[dti][1][r] = v1;
                cs0 += v0 * v0; cs1 += v1 * v1;
            }
        }
        cs0 += __shfl_xor(cs0, 16); cs0 += __shfl_xor(cs0, 32);
        cs1 += __shfl_xor(cs1, 16); cs1 += __shfl_xor(cs1, 32);
        if (lane < 16) { colsq_part[wave][lane] = cs0; colsq_part[wave][16 + lane] = cs1; }
        lds_barrier();   // colsq-b
        float sq0 = 0.f, sq1 = 0.f;
        #pragma unroll
        for (int w2 = 0; w2 < 8; ++w2) {
            sq0 += colsq_part[w2][lr];
            sq1 += colsq_part[w2][16 + lr];
        }
        float cn0 = sqrtf(sq0), cn1 = sqrtf(sq1);
        float s10 = 1.0f / fmaxf(cn0, 1e-12f);
        float s11 = 1.0f / fmaxf(cn1, 1e-12f);
        float c10 = cn0 * s10, c11 = cn1 * s11;
        float tot = c10 * c10 + c11 * c11;
        #pragma unroll
        for (int o = 1; o < 16; o <<= 1) tot += __shfl_xor(tot, o);
        float gs = 1.0f / fmaxf(sqrtf(tot), 1e-12f);
        float sk0 = s10 * gs, sk1 = s11 * gs;
        {
            float* ob = out + (size_t)bm * (DIM * KC);
            #pragma unroll
            for (int dti = 0; dti < 4; ++dti) {
                #pragma unroll
                for (int r = 0; r < 4; ++r) {
                    int d = (wave * 4 + dti) * 16 + lg * 4 + r;
                    ob[d * KC + lr]      = vacc[dti][0][r] * sk0;
                    ob[d * KC + 16 + lr] = vacc[dti][1][r] * sk1;
                }
            }
        }
        // no barrier at loop end: next phase-1 reads only own xs rows
        // (same-wave order); cross-wave xs reads happen after b1(m+1).
    }
}

extern "C" void kernel_launch(void* const* d_in, const int* in_sizes, int n_in,
                              void* d_out, int out_size, void* d_ws, size_t ws_size,
                              hipStream_t stream) {
    const float* x        = (const float*)d_in[0];
    const float* clusters = (const float*)d_in[1];
    const float* bn_w     = (const float*)d_in[2];
    const float* bn_b     = (const float*)d_in[3];
    const float* bn_rm    = (const float*)d_in[4];
    const float* bn_rv    = (const float*)d_in[5];
    const float* c2       = (const float*)d_in[6];
    float* out = (float*)d_out;

    u16*   cTs  = (u16*)d_ws;
    float* tvec = (float*)((char*)d_ws + KT * DIM * sizeof(u16));

    const int B = in_sizes[0] / (NPT * DIM);

    prep_kernel<<<KT, 256, 0, stream>>>(clusters, bn_w, bn_b, bn_rm, bn_rv, cTs, tvec);
    vlad_kernel<<<B / BPB, 512, 0, stream>>>(x, c2, cTs, tvec, out);
}

// Round 8
// 368.255 us; speedup vs baseline: 1.5456x; 1.5456x over previous
//
#include <hip/hip_runtime.h>

typedef unsigned short u16;
typedef unsigned int u32;
typedef __attribute__((ext_vector_type(8))) short short8;
typedef __attribute__((ext_vector_type(4))) float f32x4;
typedef __attribute__((ext_vector_type(4))) u32 u32x4;

#define NPT 128
#define DIM 512
#define KT 48
#define KC 32
#define BPB 16   // batches per block (persistent pipeline)

__device__ __forceinline__ u16 f2bf(float f) {
    unsigned u = __builtin_bit_cast(unsigned, f);
    return (u16)((u + 0x7FFFu + ((u >> 16) & 1u)) >> 16);
}

__device__ __forceinline__ u32 cvtpk(float lo, float hi) {
    u32 r;
    asm("v_cvt_pk_bf16_f32 %0, %1, %2" : "=v"(r) : "v"(lo), "v"(hi));
    return r;
}

// LDS-only barrier: drain this wave's LDS ops, then s_barrier. Does NOT
// drain vmcnt, so global loads/stores stay in flight across it.
__device__ __forceinline__ void lds_barrier() {
    asm volatile("s_waitcnt lgkmcnt(0)" ::: "memory");
    __builtin_amdgcn_s_barrier();
}

// bank swizzle: 16B-granular XOR inside a 1KB row
__device__ __forceinline__ int swz(int n) {
    return ((n & 7) ^ ((n >> 3) & 7)) << 4;
}

// Fold BN into clusters: cTs[k][d] = bf16(clusters[d][k] * s_k), t[k] = b_k - rm_k*s_k
__global__ void prep_kernel(const float* __restrict__ clusters,
                            const float* __restrict__ bn_w,
                            const float* __restrict__ bn_b,
                            const float* __restrict__ bn_rm,
                            const float* __restrict__ bn_rv,
                            u16* __restrict__ cTs,
                            float* __restrict__ tvec) {
    const int k = blockIdx.x;
    const float s = bn_w[k] * rsqrtf(bn_rv[k] + 1e-5f);
    if (threadIdx.x == 0) tvec[k] = bn_b[k] - bn_rm[k] * s;
    for (int d = threadIdx.x; d < DIM; d += blockDim.x)
        cTs[k * DIM + d] = f2bf(clusters[d * KT + k] * s);
}

__global__ __launch_bounds__(512)
void vlad_kernel(const float* __restrict__ x,
                 const float* __restrict__ c2,     // [512][32] fp32
                 const u16* __restrict__ cTs,      // [48][512] bf16
                 const float* __restrict__ tvec,   // [48]
                 float* __restrict__ out) {
    __shared__ __align__(16) u16 cTsL[KT * DIM];     // 48 KB, swizzled
    __shared__ __align__(16) u16 buf[2][16 * DIM];   // 2 x 16 KB chunk dbuf
    __shared__ __align__(16) u16 aT[KC][136];        // assignment^T
    __shared__ float asum_part[8][KC];
    __shared__ float colsq_part[8][KC];

    const int tid  = threadIdx.x;
    const int wave = tid >> 6;
    const int lane = tid & 63;
    const int lr   = lane & 15;
    const int lg   = lane >> 4;

    const int b0i = blockIdx.x * BPB;
    const float* xblk = x + (size_t)b0i * (NPT * DIM);

    const float t0 = tvec[lr], t1 = tvec[16 + lr], t2 = tvec[32 + lr];

    // staging role: thread t handles chunk row (t>>5), float cols (t&31)*16..+16
    const int srow = tid >> 5;
    const int scol = (tid & 31) * 16;
    const int sbyte = scol * 2;                      // bf16 byte offset in row
    const int ssw = swz(srow);

    // ---- prologue: cTs -> LDS (swizzled) ----
    #pragma unroll
    for (int i = 0; i < 6; ++i) {
        int idx = tid + i * 512;
        int k = idx >> 6, slot = idx & 63;
        u32x4 v = *(const u32x4*)(cTs + k * DIM + slot * 8);
        *(u32x4*)((char*)cTsL + k * 1024 + ((slot * 16) ^ swz(k))) = v;
    }
    // ---- prologue: stage chunk 0 into buf[0] ----
    {
        const float* g = xblk + srow * DIM + scol;
        f32x4 a0 = *(const f32x4*)(g);
        f32x4 a1 = *(const f32x4*)(g + 4);
        f32x4 a2 = *(const f32x4*)(g + 8);
        f32x4 a3 = *(const f32x4*)(g + 12);
        u32x4 wA, wB;
        wA[0] = cvtpk(a0[0], a0[1]); wA[1] = cvtpk(a0[2], a0[3]);
        wA[2] = cvtpk(a1[0], a1[1]); wA[3] = cvtpk(a1[2], a1[3]);
        wB[0] = cvtpk(a2[0], a2[1]); wB[1] = cvtpk(a2[2], a2[3]);
        wB[2] = cvtpk(a3[0], a3[1]); wB[3] = cvtpk(a3[2], a3[3]);
        char* dst = (char*)buf[0] + srow * 1024;
        *(u32x4*)(dst + (sbyte ^ ssw)) = wA;
        *(u32x4*)(dst + ((sbyte + 16) ^ ssw)) = wB;
    }
    __syncthreads();

    for (int m = 0; m < BPB; ++m) {
        f32x4 acc0 = {0.f,0.f,0.f,0.f}, acc1 = {0.f,0.f,0.f,0.f}, acc2 = {0.f,0.f,0.f,0.f};
        short8 af2[4][4];   // phase-2 A-frags: [ns][dti], filled per chunk

        // ---- chunk loop: consume chunk j, stage chunk j+1 ----
        #pragma unroll
        for (int ns = 0; ns < 4; ++ns) {
            #pragma unroll
            for (int h = 0; h < 2; ++h) {
                const int j = ns * 2 + h;
                const int cur = j & 1;
                const int gnext = m * 8 + j + 1;          // next global chunk
                const bool pOK = (gnext < BPB * 8);

                // 1) issue staging loads for chunk gnext (coalesced, 64 B/thread)
                f32x4 a0, a1, a2, a3;
                if (pOK) {
                    const float* g = xblk + (size_t)gnext * (16 * DIM) + srow * DIM + scol;
                    a0 = *(const f32x4*)(g);
                    a1 = *(const f32x4*)(g + 4);
                    a2 = *(const f32x4*)(g + 8);
                    a3 = *(const f32x4*)(g + 12);
                }

                // 2) extract phase-2 A-frag slices for this chunk (LDS only)
                if ((lane >> 5) == h) {
                    const int nb = (lg & 1) * 8;
                    #pragma unroll
                    for (int dti = 0; dti < 4; ++dti) {
                        const int dd = wave * 128 + dti * 32 + 2 * lr;   // byte = 2*d
                        short8 v;
                        #pragma unroll
                        for (int jj = 0; jj < 8; ++jj) {
                            const int rr = nb + jj;
                            v[jj] = *(const short*)((const char*)buf[cur] + rr * 1024 + (dd ^ swz(rr)));
                        }
                        af2[ns][dti] = v;
                    }
                }

                // 3) phase 1: wave j computes logits for its 16 rows (LDS only)
                if (wave == j) {
                    const char* xb = (const char*)buf[cur] + lr * 1024;
                    const int sw = swz(lr);
                    const char* c0 = (const char*)cTsL + lr * 1024;
                    const char* c1 = (const char*)cTsL + (16 + lr) * 1024;
                    const char* c2p = (const char*)cTsL + (32 + lr) * 1024;
                    const int s1 = swz(16 + lr), s2 = swz(32 + lr);
                    #pragma unroll 2
                    for (int step = 0; step < 16; ++step) {
                        const int off = step * 64 + lg * 16;
                        short8 af  = *(const short8*)(xb + (off ^ sw));
                        short8 bb0 = *(const short8*)(c0 + (off ^ sw));
                        short8 bb1 = *(const short8*)(c1 + (off ^ s1));
                        short8 bb2 = *(const short8*)(c2p + (off ^ s2));
                        acc0 = __builtin_amdgcn_mfma_f32_16x16x32_bf16(af, bb0, acc0, 0, 0, 0);
                        acc1 = __builtin_amdgcn_mfma_f32_16x16x32_bf16(af, bb1, acc1, 0, 0, 0);
                        acc2 = __builtin_amdgcn_mfma_f32_16x16x32_bf16(af, bb2, acc2, 0, 0, 0);
                    }
                }

                // 4) convert + write chunk gnext into buf[cur^1]
                if (pOK) {
                    u32x4 wA, wB;
                    wA[0] = cvtpk(a0[0], a0[1]); wA[1] = cvtpk(a0[2], a0[3]);
                    wA[2] = cvtpk(a1[0], a1[1]); wA[3] = cvtpk(a1[2], a1[3]);
                    wB[0] = cvtpk(a2[0], a2[1]); wB[1] = cvtpk(a2[2], a2[3]);
                    wB[2] = cvtpk(a3[0], a3[1]); wB[3] = cvtpk(a3[2], a3[3]);
                    char* dst = (char*)buf[cur ^ 1] + srow * 1024;
                    *(u32x4*)(dst + (sbyte ^ ssw)) = wA;
                    *(u32x4*)(dst + ((sbyte + 16) ^ ssw)) = wB;
                }
                lds_barrier();   // chunk handoff (LDS-only; vmem stays in flight)
            }
        }

        // ---- softmax over 48, keep 32; aT bf16; per-wave asum partials ----
        {
            float a0[4], a1[4];
            #pragma unroll
            for (int r = 0; r < 4; ++r) {
                float l0 = acc0[r] + t0, l1 = acc1[r] + t1, l2 = acc2[r] + t2;
                float mx = fmaxf(fmaxf(l0, l1), l2);
                #pragma unroll
                for (int o = 1; o < 16; o <<= 1) mx = fmaxf(mx, __shfl_xor(mx, o));
                float e0 = __expf(l0 - mx), e1 = __expf(l1 - mx), e2 = __expf(l2 - mx);
                float s = e0 + e1 + e2;
                #pragma unroll
                for (int o = 1; o < 16; o <<= 1) s += __shfl_xor(s, o);
                float inv = 1.0f / s;
                a0[r] = e0 * inv; a1[r] = e1 * inv;
            }
            float p0 = 0.f, p1 = 0.f;
            #pragma unroll
            for (int r = 0; r < 4; ++r) {
                int n = wave * 16 + lg * 4 + r;
                aT[lr][n]      = f2bf(a0[r]);
                aT[16 + lr][n] = f2bf(a1[r]);
                p0 += a0[r]; p1 += a1[r];
            }
            p0 += __shfl_xor(p0, 16); p0 += __shfl_xor(p0, 32);
            p1 += __shfl_xor(p1, 16); p1 += __shfl_xor(p1, 32);
            if (lane < 16) { asum_part[wave][lane] = p0; asum_part[wave][16 + lane] = p1; }
        }
        lds_barrier();   // b1: aT + asum_part ready

        // ---- phase 2: pure register A (af2) x aT B-frags ----
        f32x4 vacc[4][2];
        #pragma unroll
        for (int i = 0; i < 4; ++i) {
            vacc[i][0] = (f32x4){0.f,0.f,0.f,0.f};
            vacc[i][1] = (f32x4){0.f,0.f,0.f,0.f};
        }
        #pragma unroll
        for (int ns = 0; ns < 4; ++ns) {
            short8 bf0 = *(const short8*)(&aT[lr][ns * 32 + lg * 8]);
            short8 bf1 = *(const short8*)(&aT[16 + lr][ns * 32 + lg * 8]);
            #pragma unroll
            for (int dti = 0; dti < 4; ++dti) {
                vacc[dti][0] = __builtin_amdgcn_mfma_f32_16x16x32_bf16(af2[ns][dti], bf0, vacc[dti][0], 0, 0, 0);
                vacc[dti][1] = __builtin_amdgcn_mfma_f32_16x16x32_bf16(af2[ns][dti], bf1, vacc[dti][1], 0, 0, 0);
            }
        }

        // ---- epilogue ----
        float as0 = 0.f, as1 = 0.f;
        #pragma unroll
        for (int w2 = 0; w2 < 8; ++w2) {
            as0 += asum_part[w2][lr];
            as1 += asum_part[w2][16 + lr];
        }
        float cs0 = 0.f, cs1 = 0.f;
        #pragma unroll
        for (int dti = 0; dti < 4; ++dti) {
            #pragma unroll
            for (int r = 0; r < 4; ++r) {
                int d = (wave * 4 + dti) * 16 + lg * 4 + r;
                float v0 = vacc[dti][0][r] - as0 * c2[d * KC + lr];
                float v1 = vacc[dti][1][r] - as1 * c2[d * KC + 16 + lr];
                vacc[dti][0][r] = v0; vacc[dti][1][r] = v1;
                cs0 += v0 * v0; cs1 += v1 * v1;
            }
        }
        cs0 += __shfl_xor(cs0, 16); cs0 += __shfl_xor(cs0, 32);
        cs1 += __shfl_xor(cs1, 16); cs1 += __shfl_xor(cs1, 32);
        if (lane < 16) { colsq_part[wave][lane] = cs0; colsq_part[wave][16 + lane] = cs1; }
        lds_barrier();   // colsq-b
        float sq0 = 0.f, sq1 = 0.f;
        #pragma unroll
        for (int w2 = 0; w2 < 8; ++w2) {
            sq0 += colsq_part[w2][lr];
            sq1 += colsq_part[w2][16 + lr];
        }
        float cn0 = sqrtf(sq0), cn1 = sqrtf(sq1);
        float s10 = 1.0f / fmaxf(cn0, 1e-12f);
        float s11 = 1.0f / fmaxf(cn1, 1e-12f);
        float c10 = cn0 * s10, c11 = cn1 * s11;
        float tot = c10 * c10 + c11 * c11;
        #pragma unroll
        for (int o = 1; o < 16; o <<= 1) tot += __shfl_xor(tot, o);
        float gs = 1.0f / fmaxf(sqrtf(tot), 1e-12f);
        float sk0 = s10 * gs, sk1 = s11 * gs;
        {
            float* ob = out + (size_t)(b0i + m) * (DIM * KC);
            #pragma unroll
            for (int dti = 0; dti < 4; ++dti) {
                #pragma unroll
                for (int r = 0; r < 4; ++r) {
                    int d = (wave * 4 + dti) * 16 + lg * 4 + r;
                    ob[d * KC + lr]      = vacc[dti][0][r] * sk0;
                    ob[d * KC + 16 + lr] = vacc[dti][1][r] * sk1;
                }
            }
        }
        // next batch's chunk 0 was staged at j=7 into buf[0]; barriers above
        // separate its writes from the next chunk loop's readers.
    }
}

extern "C" void kernel_launch(void* const* d_in, const int* in_sizes, int n_in,
                              void* d_out, int out_size, void* d_ws, size_t ws_size,
                              hipStream_t stream) {
    const float* x        = (const float*)d_in[0];
    const float* clusters = (const float*)d_in[1];
    const float* bn_w     = (const float*)d_in[2];
    const float* bn_b     = (const float*)d_in[3];
    const float* bn_rm    = (const float*)d_in[4];
    const float* bn_rv    = (const float*)d_in[5];
    const float* c2       = (const float*)d_in[6];
    float* out = (float*)d_out;

    u16*   cTs  = (u16*)d_ws;
    float* tvec = (float*)((char*)d_ws + KT * DIM * sizeof(u16));

    const int B = in_sizes[0] / (NPT * DIM);

    prep_kernel<<<KT, 256, 0, stream>>>(clusters, bn_w, bn_b, bn_rm, bn_rv, cTs, tvec);
    vlad_kernel<<<B / BPB, 512, 0, stream>>>(x, c2, cTs, tvec, out);
}